// Round 4
// baseline (10374.905 us; speedup 1.0000x reference)
//
#include <hip/hip_runtime.h>
#include <hip/hip_bf16.h>

#define USER_N   100000
#define ITEM_N   200000
#define N_NODES  300000           // USER_N + ITEM_N
#define LATDIM   64
#define N_EDGES  9600000
#define N_LAYERS 3

// coarse tiles: 256 rows per bucket
#define TSHIFT    8
#define TILE_ROWS 256
#define NB2       ((N_NODES + TILE_ROWS - 1) / TILE_ROWS)   // 1172
#define GPART     512                                        // partition blocks
#define EPB       ((N_EDGES + GPART - 1) / GPART)            // 18750 edges/block
#define SEG2      2                                          // ceil(NB2/1024)

// ---------------------------------------------------------------------------
// copy concat(u, i) -> cur (ws) and acc (d_out), float4-vectorized
// ---------------------------------------------------------------------------
__global__ void copy_concat_kernel(const float* __restrict__ u,
                                   const float* __restrict__ it,
                                   float* __restrict__ cur,
                                   float* __restrict__ acc,
                                   int n4u, int n4total) {
    int stride = gridDim.x * blockDim.x;
    for (int i = blockIdx.x * blockDim.x + threadIdx.x; i < n4total; i += stride) {
        float4 v = (i < n4u) ? ((const float4*)u)[i]
                             : ((const float4*)it)[i - n4u];
        ((float4*)cur)[i] = v;
        ((float4*)acc)[i] = v;
    }
}

// ---------------------------------------------------------------------------
// P1: per-block bucket histogram over its contiguous edge slice.
// cnt laid out bucket-major: cnt[bucket * GPART + block]
// ---------------------------------------------------------------------------
__global__ void p1_count_kernel(const int* __restrict__ row,
                                int* __restrict__ cnt) {
    __shared__ int h[NB2];
    int blk = blockIdx.x, t = threadIdx.x;
    for (int i = t; i < NB2; i += 256) h[i] = 0;
    __syncthreads();
    int e0 = blk * EPB;
    int e1 = e0 + EPB; if (e1 > N_EDGES) e1 = N_EDGES;
    for (int e = e0 + t; e < e1; e += 256)
        atomicAdd(&h[row[e] >> TSHIFT], 1);
    __syncthreads();
    for (int i = t; i < NB2; i += 256)
        cnt[i * GPART + blk] = h[i];
}

// ---------------------------------------------------------------------------
// P2: per-bucket scan of its GPART block-counts -> exclusive offsets in place,
// bucket total to btot.  One block (512 thr) per bucket.
// ---------------------------------------------------------------------------
__global__ void p2_scan_kernel(int* __restrict__ cnt, int* __restrict__ btot) {
    __shared__ int lds[GPART];
    int b = blockIdx.x, t = threadIdx.x;
    int v = cnt[b * GPART + t];
    lds[t] = v;
    __syncthreads();
    for (int off = 1; off < GPART; off <<= 1) {
        int add = (t >= off) ? lds[t - off] : 0;
        __syncthreads();
        lds[t] += add;
        __syncthreads();
    }
    cnt[b * GPART + t] = lds[t] - v;          // exclusive within bucket
    if (t == GPART - 1) btot[b] = lds[t];
}

// ---------------------------------------------------------------------------
// P3: exclusive scan of NB2 bucket totals (single block, 1024 thr, SEG2 each)
// ---------------------------------------------------------------------------
__global__ void p3_scan_kernel(const int* __restrict__ btot,
                               int* __restrict__ bstart) {
    __shared__ int lds[1024];
    int t = threadIdx.x;
    int i0 = t * SEG2, i1 = i0 + 1;
    int a = (i0 < NB2) ? btot[i0] : 0;
    int c = (i1 < NB2) ? btot[i1] : 0;
    int s = a + c;
    lds[t] = s;
    __syncthreads();
    for (int off = 1; off < 1024; off <<= 1) {
        int add = (t >= off) ? lds[t - off] : 0;
        __syncthreads();
        lds[t] += add;
        __syncthreads();
    }
    int ex = lds[t] - s;
    if (i0 < NB2) bstart[i0] = ex;
    if (i1 < NB2) bstart[i1] = ex + a;
    if (t == 1023) bstart[NB2] = lds[1023];   // = N_EDGES
}

// ---------------------------------------------------------------------------
// P4: scatter edges into bucket-grouped temp. Each block writes exclusive
// per-bucket runs (~128B) -> near-1x write amplification, no cross-XCD
// line sharing except run boundaries.
// entry: key = row_local(8b)<<19 | col(19b), val bits
// ---------------------------------------------------------------------------
__global__ void p4_scatter_kernel(const int*   __restrict__ row,
                                  const int*   __restrict__ col,
                                  const float* __restrict__ val,
                                  const int*   __restrict__ bstart,
                                  const int*   __restrict__ cnt,
                                  int2*        __restrict__ temp) {
    __shared__ int cur[NB2];
    int blk = blockIdx.x, t = threadIdx.x;
    for (int i = t; i < NB2; i += 256)
        cur[i] = bstart[i] + cnt[i * GPART + blk];
    __syncthreads();
    int e0 = blk * EPB;
    int e1 = e0 + EPB; if (e1 > N_EDGES) e1 = N_EDGES;
    for (int e = e0 + t; e < e1; e += 256) {
        int r = row[e];
        int b = r >> TSHIFT;
        int pos = atomicAdd(&cur[b], 1);
        temp[pos] = make_int2(((r & (TILE_ROWS - 1)) << 19) | col[e],
                              __float_as_int(val[e]));
    }
}

// ---------------------------------------------------------------------------
// SpMM from coarse buckets: one block per bucket, 64KB LDS accumulator
// (256 rows x 64 dims f32). Lane d of a wave owns dim d; 256B coalesced
// gather per edge; ds_add_f32 accumulate (2-way bank alias = free).
// Fused: acc += tile; nxt = tile (storeY).
// ---------------------------------------------------------------------------
__global__ __launch_bounds__(512)
void spmm_lds_kernel(const int*  __restrict__ bstart,
                     const int2* __restrict__ cv,
                     const float* __restrict__ x,
                     float*       __restrict__ y,
                     float*       __restrict__ acc,
                     int storeY) {
    __shared__ float tile[TILE_ROWS * LATDIM];          // 64 KB
    int b = blockIdx.x;
    int t = threadIdx.x;
    float4* t4 = (float4*)tile;
    for (int i = t; i < TILE_ROWS * 16; i += 512)
        t4[i] = make_float4(0.f, 0.f, 0.f, 0.f);
    __syncthreads();

    int beg = bstart[b];
    int end = bstart[b + 1];
    int lane = t & 63;
    int w = t >> 6;                                     // 8 waves

    for (int e = beg + w * 8; e < end; e += 64) {       // 8 edges/wave in flight
        int m = end - e; if (m > 8) m = 8;
        int2 meta[8]; float g[8];
        #pragma unroll
        for (int k = 0; k < 8; ++k) if (k < m) meta[k] = cv[e + k];
        #pragma unroll
        for (int k = 0; k < 8; ++k) if (k < m)
            g[k] = x[(size_t)(meta[k].x & 0x7FFFF) * LATDIM + lane];
        #pragma unroll
        for (int k = 0; k < 8; ++k) if (k < m) {
            float v = __int_as_float(meta[k].y);
            atomicAdd(&tile[(((unsigned)meta[k].x) >> 19) * LATDIM + lane],
                      g[k] * v);
        }
    }
    __syncthreads();

    size_t base = (size_t)b * (TILE_ROWS * 16);
    const size_t limit = (size_t)N_NODES * 16;
    float4* acc4 = (float4*)acc;
    float4* y4   = (float4*)y;
    for (int i = t; i < TILE_ROWS * 16; i += 512) {
        size_t o = base + i;
        if (o < limit) {
            float4 v = t4[i];
            float4 a = acc4[o];
            a.x += v.x; a.y += v.y; a.z += v.z; a.w += v.w;
            acc4[o] = a;
            if (storeY) y4[o] = v;
        }
    }
}

// ---------------------------------------------------------------------------
// Fallback path (R0): COO atomic SpMM + acc add
// ---------------------------------------------------------------------------
__global__ void spmm_atomic_kernel(const int*   __restrict__ row,
                                   const int*   __restrict__ col,
                                   const float* __restrict__ val,
                                   const float* __restrict__ x,
                                   float*       __restrict__ y) {
    const int total = N_EDGES * 16;
    int stride = gridDim.x * blockDim.x;
    for (int t = blockIdx.x * blockDim.x + threadIdx.x; t < total; t += stride) {
        int e = t >> 4;
        int q = t & 15;
        int r = row[e];
        int c = col[e];
        float v = val[e];
        float4 g = ((const float4*)x)[c * 16 + q];
        float* yp = y + r * 64 + q * 4;
        atomicAdd(yp + 0, g.x * v);
        atomicAdd(yp + 1, g.y * v);
        atomicAdd(yp + 2, g.z * v);
        atomicAdd(yp + 3, g.w * v);
    }
}

__global__ void acc_add_kernel(float* __restrict__ acc,
                               const float* __restrict__ add,
                               int n4) {
    int stride = gridDim.x * blockDim.x;
    for (int i = blockIdx.x * blockDim.x + threadIdx.x; i < n4; i += stride) {
        float4 a = ((const float4*)acc)[i];
        float4 b = ((const float4*)add)[i];
        a.x += b.x; a.y += b.y; a.z += b.z; a.w += b.w;
        ((float4*)acc)[i] = a;
    }
}

extern "C" void kernel_launch(void* const* d_in, const int* in_sizes, int n_in,
                              void* d_out, int out_size, void* d_ws, size_t ws_size,
                              hipStream_t stream) {
    const float* uEmb = (const float*)d_in[0];
    const float* iEmb = (const float*)d_in[1];
    const int*   row  = (const int*)  d_in[2];
    const int*   col  = (const int*)  d_in[3];
    const float* val  = (const float*)d_in[4];

    float* acc = (float*)d_out;

    const int n4total = N_NODES * (LATDIM / 4);
    const int n4u     = USER_N  * (LATDIM / 4);
    const size_t embBytes = (size_t)N_NODES * LATDIM * sizeof(float);

    const int BLK = 256;
    const int GRID_MEM = 2048;

    // ---- workspace layout ----
    auto align256 = [](size_t x) { return (x + 255) & ~(size_t)255; };
    size_t off = 0;
    size_t o_cur    = off; off += align256(embBytes);
    size_t o_nxt    = off; off += align256(embBytes);
    size_t o_temp   = off; off += align256((size_t)N_EDGES * 8);
    size_t o_cnt    = off; off += align256((size_t)NB2 * GPART * 4);
    size_t o_btot   = off; off += align256((size_t)NB2 * 4);
    size_t o_bstart = off; off += align256(((size_t)NB2 + 1) * 4);
    size_t needed = off;

    char* wsb = (char*)d_ws;
    float* cur0 = (float*)(wsb + o_cur);
    float* nxt0 = (float*)(wsb + o_nxt);

    if (ws_size >= needed) {
        // ============ bucketed LDS-accumulate path ============
        int2* temp   = (int2*)(wsb + o_temp);
        int*  cnt    = (int*) (wsb + o_cnt);
        int*  btot   = (int*) (wsb + o_btot);
        int*  bstart = (int*) (wsb + o_bstart);

        copy_concat_kernel<<<GRID_MEM, BLK, 0, stream>>>(uEmb, iEmb, cur0, acc,
                                                         n4u, n4total);

        p1_count_kernel  <<<GPART, 256, 0, stream>>>(row, cnt);
        p2_scan_kernel   <<<NB2, GPART, 0, stream>>>(cnt, btot);
        p3_scan_kernel   <<<1, 1024, 0, stream>>>(btot, bstart);
        p4_scatter_kernel<<<GPART, 256, 0, stream>>>(row, col, val, bstart,
                                                     cnt, temp);

        float* cur = cur0;
        float* nxt = nxt0;
        for (int l = 0; l < N_LAYERS; ++l) {
            int storeY = (l != N_LAYERS - 1);
            spmm_lds_kernel<<<NB2, 512, 0, stream>>>(bstart, temp, cur,
                                                     nxt, acc, storeY);
            float* t = cur; cur = nxt; nxt = t;
        }
    } else {
        // ============ fallback: atomic path ============
        copy_concat_kernel<<<GRID_MEM, BLK, 0, stream>>>(uEmb, iEmb, cur0, acc,
                                                         n4u, n4total);
        float* cur = cur0;
        float* nxt = nxt0;
        for (int l = 0; l < N_LAYERS; ++l) {
            hipMemsetAsync(nxt, 0, embBytes, stream);
            spmm_atomic_kernel<<<4096, BLK, 0, stream>>>(row, col, val, cur, nxt);
            acc_add_kernel<<<GRID_MEM, BLK, 0, stream>>>(acc, nxt, n4total);
            float* t = cur; cur = nxt; nxt = t;
        }
    }
}

// Round 5
// 1475.163 us; speedup vs baseline: 7.0331x; 7.0331x over previous
//
#include <hip/hip_runtime.h>
#include <hip/hip_bf16.h>

#define USER_N   100000
#define ITEM_N   200000
#define N_NODES  300000           // USER_N + ITEM_N
#define LATDIM   64
#define N_EDGES  9600000
#define N_LAYERS 3

// 64-row buckets
#define B_SHIFT  6
#define B_ROWS   64
#define NB       ((N_NODES + B_ROWS - 1) / B_ROWS)    // 4688
#define GPART    512                                   // partition slices
#define EPB      ((N_EDGES + GPART - 1) / GPART)       // 18750 (exact: 512*18750)
#define SEG      5                                     // ceil(NB/1024)
#define CAP      3072                                  // LDS stage entries (avg 2048)

// ---------------------------------------------------------------------------
// copy concat(u, i) -> cur (ws) and acc (d_out), float4-vectorized
// ---------------------------------------------------------------------------
__global__ void copy_concat_kernel(const float* __restrict__ u,
                                   const float* __restrict__ it,
                                   float* __restrict__ cur,
                                   float* __restrict__ acc,
                                   int n4u, int n4total) {
    int stride = gridDim.x * blockDim.x;
    for (int i = blockIdx.x * blockDim.x + threadIdx.x; i < n4total; i += stride) {
        float4 v = (i < n4u) ? ((const float4*)u)[i]
                             : ((const float4*)it)[i - n4u];
        ((float4*)cur)[i] = v;
        ((float4*)acc)[i] = v;
    }
}

// slice swizzle: adjacent slices (adjacent runs in each bucket) live on the
// same XCD (blockIdx round-robins XCDs; blk and blk+8 share an XCD)
__device__ __forceinline__ int slice_of(int blk) {
    return ((blk & 7) << 6) | (blk >> 3);
}

// ---------------------------------------------------------------------------
// P1: per-slice bucket histogram (LDS), no global atomics.
// cnt[bucket * GPART + slice]
// ---------------------------------------------------------------------------
__global__ void p1_count_kernel(const int* __restrict__ row,
                                int* __restrict__ cnt) {
    __shared__ int h[NB];
    int s = slice_of(blockIdx.x), t = threadIdx.x;
    for (int i = t; i < NB; i += 256) h[i] = 0;
    __syncthreads();
    int e0 = s * EPB;
    int e1 = e0 + EPB; if (e1 > N_EDGES) e1 = N_EDGES;
    for (int e = e0 + t; e < e1; e += 256)
        atomicAdd(&h[row[e] >> B_SHIFT], 1);
    __syncthreads();
    for (int i = t; i < NB; i += 256)
        cnt[i * GPART + s] = h[i];
}

// ---------------------------------------------------------------------------
// P2: per-bucket exclusive scan of its GPART slice-counts; total -> btot
// ---------------------------------------------------------------------------
__global__ void p2_scan_kernel(int* __restrict__ cnt, int* __restrict__ btot) {
    __shared__ int lds[GPART];
    int b = blockIdx.x, t = threadIdx.x;
    int v = cnt[b * GPART + t];
    lds[t] = v;
    __syncthreads();
    for (int off = 1; off < GPART; off <<= 1) {
        int add = (t >= off) ? lds[t - off] : 0;
        __syncthreads();
        lds[t] += add;
        __syncthreads();
    }
    cnt[b * GPART + t] = lds[t] - v;
    if (t == GPART - 1) btot[b] = lds[t];
}

// ---------------------------------------------------------------------------
// P3: exclusive scan of NB bucket totals (1 block, 1024 thr, SEG each)
// ---------------------------------------------------------------------------
__global__ void p3_scan_kernel(const int* __restrict__ btot,
                               int* __restrict__ bstart,
                               int* __restrict__ rowPtr) {
    __shared__ int lds[1024];
    int t = threadIdx.x;
    int base = t * SEG;
    int loc[SEG];
    int s = 0;
    #pragma unroll
    for (int k = 0; k < SEG; ++k) {
        int i = base + k;
        int v = (i < NB) ? btot[i] : 0;
        loc[k] = v;
        s += v;
    }
    lds[t] = s;
    __syncthreads();
    for (int off = 1; off < 1024; off <<= 1) {
        int add = (t >= off) ? lds[t - off] : 0;
        __syncthreads();
        lds[t] += add;
        __syncthreads();
    }
    int ex = lds[t] - s;
    #pragma unroll
    for (int k = 0; k < SEG; ++k) {
        int i = base + k;
        if (i < NB) bstart[i] = ex;
        ex += loc[k];
    }
    if (t == 1023) {
        bstart[NB] = lds[1023];          // = N_EDGES
        rowPtr[N_NODES] = N_EDGES;
    }
}

// ---------------------------------------------------------------------------
// P4: scatter edges into bucket-grouped temp; each slice writes exclusive
// runs (~4 entries), adjacent runs on same XCD. key = rl(6b)<<19 | col(19b)
// ---------------------------------------------------------------------------
__global__ void p4_scatter_kernel(const int*   __restrict__ row,
                                  const int*   __restrict__ col,
                                  const float* __restrict__ val,
                                  const int*   __restrict__ bstart,
                                  const int*   __restrict__ cnt,
                                  int2*        __restrict__ temp) {
    __shared__ int cur[NB];
    int s = slice_of(blockIdx.x), t = threadIdx.x;
    for (int i = t; i < NB; i += 256)
        cur[i] = bstart[i] + cnt[i * GPART + s];
    __syncthreads();
    int e0 = s * EPB;
    int e1 = e0 + EPB; if (e1 > N_EDGES) e1 = N_EDGES;
    for (int e = e0 + t; e < e1; e += 256) {
        int r = row[e];
        int b = r >> B_SHIFT;
        int pos = atomicAdd(&cur[b], 1);
        temp[pos] = make_int2(((r & (B_ROWS - 1)) << 19) | col[e],
                              __float_as_int(val[e]));
    }
}

// ---------------------------------------------------------------------------
// P5: per-bucket counting sort (~2048 entries). Sorted entries staged in LDS,
// flushed coalesced; also emits rowPtr. Overflow (>CAP) scatters direct.
// ---------------------------------------------------------------------------
__global__ __launch_bounds__(256)
void bucket_sort_kernel(const int*  __restrict__ bstart,
                        const int2* __restrict__ temp,
                        int2*       __restrict__ colval,
                        int*        __restrict__ rowPtr) {
    __shared__ int hist[B_ROWS];
    __shared__ int curs[B_ROWS];
    __shared__ int2 stage[CAP];
    int b = blockIdx.x, t = threadIdx.x;
    int beg = bstart[b];
    int end = bstart[b + 1];
    int n = end - beg;

    if (t < B_ROWS) hist[t] = 0;
    __syncthreads();
    for (int i = beg + t; i < end; i += 256)
        atomicAdd(&hist[((unsigned)temp[i].x) >> 19], 1);
    __syncthreads();

    if (t < B_ROWS) {                      // first wave: shfl inclusive scan
        int v = hist[t];
        int inc = v;
        #pragma unroll
        for (int d = 1; d < B_ROWS; d <<= 1) {
            int o = __shfl_up(inc, d, 64);
            if (t >= d) inc += o;
        }
        int ex = inc - v;
        curs[t] = ex;
        int r = (b << B_SHIFT) + t;
        if (r < N_NODES) rowPtr[r] = beg + ex;
    }
    __syncthreads();

    for (int i = beg + t; i < end; i += 256) {
        int2 kv = temp[i];
        int rl = ((unsigned)kv.x) >> 19;
        int p  = atomicAdd(&curs[rl], 1);
        int2 out = make_int2(kv.x & 0x7FFFF, kv.y);
        if (p < CAP) stage[p] = out;
        else         colval[beg + p] = out;      // (never for this input)
    }
    __syncthreads();

    int lim = (n < CAP) ? n : CAP;
    for (int i = t; i < lim; i += 256)
        colval[beg + i] = stage[i];              // coalesced flush
}

// ---------------------------------------------------------------------------
// CSR SpMM, atomic-free (R1-proven): 16 lanes/row, lane q owns dims [4q,4q+4)
// ---------------------------------------------------------------------------
__global__ void spmm_csr_kernel(const int*  __restrict__ rp,
                                const int2* __restrict__ cv,
                                const float* __restrict__ x,
                                float*       __restrict__ y,
                                float*       __restrict__ acc,
                                int storeY) {
    int g = (blockIdx.x * blockDim.x + threadIdx.x) >> 4;   // row
    if (g >= N_NODES) return;
    int q = threadIdx.x & 15;
    int beg = rp[g];
    int end = rp[g + 1];
    const float4* x4 = (const float4*)x;

    float4 s = make_float4(0.f, 0.f, 0.f, 0.f);
    int i = beg;
    for (; i + 4 <= end; i += 4) {
        int2 c0 = cv[i], c1 = cv[i + 1], c2 = cv[i + 2], c3 = cv[i + 3];
        float4 g0 = x4[(size_t)c0.x * 16 + q];
        float4 g1 = x4[(size_t)c1.x * 16 + q];
        float4 g2 = x4[(size_t)c2.x * 16 + q];
        float4 g3 = x4[(size_t)c3.x * 16 + q];
        float v0 = __int_as_float(c0.y), v1 = __int_as_float(c1.y);
        float v2 = __int_as_float(c2.y), v3 = __int_as_float(c3.y);
        s.x += g0.x * v0; s.y += g0.y * v0; s.z += g0.z * v0; s.w += g0.w * v0;
        s.x += g1.x * v1; s.y += g1.y * v1; s.z += g1.z * v1; s.w += g1.w * v1;
        s.x += g2.x * v2; s.y += g2.y * v2; s.z += g2.z * v2; s.w += g2.w * v2;
        s.x += g3.x * v3; s.y += g3.y * v3; s.z += g3.z * v3; s.w += g3.w * v3;
    }
    for (; i < end; ++i) {
        int2 cc = cv[i];
        float4 gg = x4[(size_t)cc.x * 16 + q];
        float v  = __int_as_float(cc.y);
        s.x += gg.x * v; s.y += gg.y * v; s.z += gg.z * v; s.w += gg.w * v;
    }

    size_t o = (size_t)g * 16 + q;
    float4 a = ((const float4*)acc)[o];
    a.x += s.x; a.y += s.y; a.z += s.z; a.w += s.w;
    ((float4*)acc)[o] = a;
    if (storeY) ((float4*)y)[o] = s;
}

// ---------------------------------------------------------------------------
// Fallback path: COO atomic SpMM + acc add
// ---------------------------------------------------------------------------
__global__ void spmm_atomic_kernel(const int*   __restrict__ row,
                                   const int*   __restrict__ col,
                                   const float* __restrict__ val,
                                   const float* __restrict__ x,
                                   float*       __restrict__ y) {
    const int total = N_EDGES * 16;
    int stride = gridDim.x * blockDim.x;
    for (int t = blockIdx.x * blockDim.x + threadIdx.x; t < total; t += stride) {
        int e = t >> 4;
        int q = t & 15;
        int r = row[e];
        int c = col[e];
        float v = val[e];
        float4 g = ((const float4*)x)[c * 16 + q];
        float* yp = y + r * 64 + q * 4;
        atomicAdd(yp + 0, g.x * v);
        atomicAdd(yp + 1, g.y * v);
        atomicAdd(yp + 2, g.z * v);
        atomicAdd(yp + 3, g.w * v);
    }
}

__global__ void acc_add_kernel(float* __restrict__ acc,
                               const float* __restrict__ add,
                               int n4) {
    int stride = gridDim.x * blockDim.x;
    for (int i = blockIdx.x * blockDim.x + threadIdx.x; i < n4; i += stride) {
        float4 a = ((const float4*)acc)[i];
        float4 b = ((const float4*)add)[i];
        a.x += b.x; a.y += b.y; a.z += b.z; a.w += b.w;
        ((float4*)acc)[i] = a;
    }
}

extern "C" void kernel_launch(void* const* d_in, const int* in_sizes, int n_in,
                              void* d_out, int out_size, void* d_ws, size_t ws_size,
                              hipStream_t stream) {
    const float* uEmb = (const float*)d_in[0];
    const float* iEmb = (const float*)d_in[1];
    const int*   row  = (const int*)  d_in[2];
    const int*   col  = (const int*)  d_in[3];
    const float* val  = (const float*)d_in[4];

    float* acc = (float*)d_out;

    const int n4total = N_NODES * (LATDIM / 4);
    const int n4u     = USER_N  * (LATDIM / 4);
    const size_t embBytes = (size_t)N_NODES * LATDIM * sizeof(float);

    const int BLK = 256;
    const int GRID_MEM = 2048;

    // ---- workspace layout ----
    auto align256 = [](size_t x) { return (x + 255) & ~(size_t)255; };
    size_t off = 0;
    size_t o_cur    = off; off += align256(embBytes);
    size_t o_nxt    = off; off += align256(embBytes);      // temp aliases this
    size_t o_colval = off; off += align256((size_t)N_EDGES * 8);
    size_t o_rowptr = off; off += align256(((size_t)N_NODES + 1) * 4);
    size_t o_cnt    = off; off += align256((size_t)NB * GPART * 4);
    size_t o_btot   = off; off += align256((size_t)NB * 4);
    size_t o_bstart = off; off += align256(((size_t)NB + 1) * 4);
    size_t needed = off;

    char* wsb = (char*)d_ws;
    float* cur0 = (float*)(wsb + o_cur);
    float* nxt0 = (float*)(wsb + o_nxt);

    if (ws_size >= needed) {
        // ============ sorted-CSR path ============
        int2* colval = (int2*)(wsb + o_colval);
        int*  rowPtr = (int*) (wsb + o_rowptr);
        int*  cnt    = (int*) (wsb + o_cnt);
        int*  btot   = (int*) (wsb + o_btot);
        int*  bstart = (int*) (wsb + o_bstart);
        int2* temp   = (int2*)nxt0;    // consumed before layer-0 writes nxt

        copy_concat_kernel<<<GRID_MEM, BLK, 0, stream>>>(uEmb, iEmb, cur0, acc,
                                                         n4u, n4total);

        p1_count_kernel  <<<GPART, 256, 0, stream>>>(row, cnt);
        p2_scan_kernel   <<<NB, GPART, 0, stream>>>(cnt, btot);
        p3_scan_kernel   <<<1, 1024, 0, stream>>>(btot, bstart, rowPtr);
        p4_scatter_kernel<<<GPART, 256, 0, stream>>>(row, col, val, bstart,
                                                     cnt, temp);
        bucket_sort_kernel<<<NB, 256, 0, stream>>>(bstart, temp, colval, rowPtr);

        const int GRID_SPMM = (N_NODES * 16 + BLK - 1) / BLK;   // 18750
        float* cur = cur0;
        float* nxt = nxt0;
        for (int l = 0; l < N_LAYERS; ++l) {
            int storeY = (l != N_LAYERS - 1);
            spmm_csr_kernel<<<GRID_SPMM, BLK, 0, stream>>>(rowPtr, colval, cur,
                                                           nxt, acc, storeY);
            float* t = cur; cur = nxt; nxt = t;
        }
    } else {
        // ============ fallback: atomic path ============
        copy_concat_kernel<<<GRID_MEM, BLK, 0, stream>>>(uEmb, iEmb, cur0, acc,
                                                         n4u, n4total);
        float* cur = cur0;
        float* nxt = nxt0;
        for (int l = 0; l < N_LAYERS; ++l) {
            hipMemsetAsync(nxt, 0, embBytes, stream);
            spmm_atomic_kernel<<<4096, BLK, 0, stream>>>(row, col, val, cur, nxt);
            acc_add_kernel<<<GRID_MEM, BLK, 0, stream>>>(acc, nxt, n4total);
            float* t = cur; cur = nxt; nxt = t;
        }
    }
}

// Round 6
// 926.133 us; speedup vs baseline: 11.2024x; 1.5928x over previous
//
#include <hip/hip_runtime.h>
#include <hip/hip_bf16.h>

#define USER_N   100000
#define ITEM_N   200000
#define N_NODES  300000           // USER_N + ITEM_N
#define LATDIM   64
#define N_EDGES  9600000
#define N_LAYERS 3

// 64-row buckets
#define B_SHIFT  6
#define B_ROWS   64
#define NB       ((N_NODES + B_ROWS - 1) / B_ROWS)    // 4688
#define GPART    512                                   // partition slices
#define EPB      ((N_EDGES + GPART - 1) / GPART)       // 18750
#define SEG      5                                     // ceil(NB/1024)
#define CAP      3072                                  // LDS stage entries

// ---- bf16 helpers (RNE) ----
__device__ __forceinline__ unsigned short f2bf(float f) {
    unsigned int u = __float_as_uint(f);
    u += 0x7FFFu + ((u >> 16) & 1u);
    return (unsigned short)(u >> 16);
}
__device__ __forceinline__ float bf2f(unsigned short h) {
    return __uint_as_float(((unsigned int)h) << 16);
}

// ---------------------------------------------------------------------------
// convert concat(u,i) fp32 -> bf16 cur0
// ---------------------------------------------------------------------------
__global__ void cvt_concat_kernel(const float* __restrict__ u,
                                  const float* __restrict__ it,
                                  ushort4* __restrict__ cur0,
                                  int n4u, int n4total) {
    int stride = gridDim.x * blockDim.x;
    for (int i = blockIdx.x * blockDim.x + threadIdx.x; i < n4total; i += stride) {
        float4 v = (i < n4u) ? ((const float4*)u)[i]
                             : ((const float4*)it)[i - n4u];
        ushort4 o;
        o.x = f2bf(v.x); o.y = f2bf(v.y); o.z = f2bf(v.z); o.w = f2bf(v.w);
        cur0[i] = o;
    }
}

// slice swizzle: adjacent slices live on the same XCD
__device__ __forceinline__ int slice_of(int blk) {
    return ((blk & 7) << 6) | (blk >> 3);
}

// ---------------------------------------------------------------------------
// P1: per-slice bucket histogram (LDS). cnt[bucket * GPART + slice]
// ---------------------------------------------------------------------------
__global__ void p1_count_kernel(const int* __restrict__ row,
                                int* __restrict__ cnt) {
    __shared__ int h[NB];
    int s = slice_of(blockIdx.x), t = threadIdx.x;
    for (int i = t; i < NB; i += 256) h[i] = 0;
    __syncthreads();
    int e0 = s * EPB;
    int e1 = e0 + EPB; if (e1 > N_EDGES) e1 = N_EDGES;
    for (int e = e0 + t; e < e1; e += 256)
        atomicAdd(&h[row[e] >> B_SHIFT], 1);
    __syncthreads();
    for (int i = t; i < NB; i += 256)
        cnt[i * GPART + s] = h[i];
}

// ---------------------------------------------------------------------------
// P2: per-bucket exclusive scan of its GPART slice-counts; total -> btot
// ---------------------------------------------------------------------------
__global__ void p2_scan_kernel(int* __restrict__ cnt, int* __restrict__ btot) {
    __shared__ int lds[GPART];
    int b = blockIdx.x, t = threadIdx.x;
    int v = cnt[b * GPART + t];
    lds[t] = v;
    __syncthreads();
    for (int off = 1; off < GPART; off <<= 1) {
        int add = (t >= off) ? lds[t - off] : 0;
        __syncthreads();
        lds[t] += add;
        __syncthreads();
    }
    cnt[b * GPART + t] = lds[t] - v;
    if (t == GPART - 1) btot[b] = lds[t];
}

// ---------------------------------------------------------------------------
// P3: exclusive scan of NB bucket totals (1 block, 1024 thr, SEG each)
// ---------------------------------------------------------------------------
__global__ void p3_scan_kernel(const int* __restrict__ btot,
                               int* __restrict__ bstart,
                               int* __restrict__ rowPtr) {
    __shared__ int lds[1024];
    int t = threadIdx.x;
    int base = t * SEG;
    int loc[SEG];
    int s = 0;
    #pragma unroll
    for (int k = 0; k < SEG; ++k) {
        int i = base + k;
        int v = (i < NB) ? btot[i] : 0;
        loc[k] = v;
        s += v;
    }
    lds[t] = s;
    __syncthreads();
    for (int off = 1; off < 1024; off <<= 1) {
        int add = (t >= off) ? lds[t - off] : 0;
        __syncthreads();
        lds[t] += add;
        __syncthreads();
    }
    int ex = lds[t] - s;
    #pragma unroll
    for (int k = 0; k < SEG; ++k) {
        int i = base + k;
        if (i < NB) bstart[i] = ex;
        ex += loc[k];
    }
    if (t == 1023) {
        bstart[NB] = lds[1023];          // = N_EDGES
        rowPtr[N_NODES] = N_EDGES;
    }
}

// ---------------------------------------------------------------------------
// P4: scatter edges into bucket-grouped temp; slice-exclusive runs.
// key = rl(6b)<<19 | col(19b)
// ---------------------------------------------------------------------------
__global__ void p4_scatter_kernel(const int*   __restrict__ row,
                                  const int*   __restrict__ col,
                                  const float* __restrict__ val,
                                  const int*   __restrict__ bstart,
                                  const int*   __restrict__ cnt,
                                  int2*        __restrict__ temp) {
    __shared__ int cur[NB];
    int s = slice_of(blockIdx.x), t = threadIdx.x;
    for (int i = t; i < NB; i += 256)
        cur[i] = bstart[i] + cnt[i * GPART + s];
    __syncthreads();
    int e0 = s * EPB;
    int e1 = e0 + EPB; if (e1 > N_EDGES) e1 = N_EDGES;
    for (int e = e0 + t; e < e1; e += 256) {
        int r = row[e];
        int b = r >> B_SHIFT;
        int pos = atomicAdd(&cur[b], 1);
        temp[pos] = make_int2(((r & (B_ROWS - 1)) << 19) | col[e],
                              __float_as_int(val[e]));
    }
}

// ---------------------------------------------------------------------------
// P5: per-bucket counting sort; staged in LDS, flushed coalesced; emits rowPtr
// ---------------------------------------------------------------------------
__global__ __launch_bounds__(256)
void bucket_sort_kernel(const int*  __restrict__ bstart,
                        const int2* __restrict__ temp,
                        int2*       __restrict__ colval,
                        int*        __restrict__ rowPtr) {
    __shared__ int hist[B_ROWS];
    __shared__ int curs[B_ROWS];
    __shared__ int2 stage[CAP];
    int b = blockIdx.x, t = threadIdx.x;
    int beg = bstart[b];
    int end = bstart[b + 1];
    int n = end - beg;

    if (t < B_ROWS) hist[t] = 0;
    __syncthreads();
    for (int i = beg + t; i < end; i += 256)
        atomicAdd(&hist[((unsigned)temp[i].x) >> 19], 1);
    __syncthreads();

    if (t < B_ROWS) {                      // first wave: shfl inclusive scan
        int v = hist[t];
        int inc = v;
        #pragma unroll
        for (int d = 1; d < B_ROWS; d <<= 1) {
            int o = __shfl_up(inc, d, 64);
            if (t >= d) inc += o;
        }
        int ex = inc - v;
        curs[t] = ex;
        int r = (b << B_SHIFT) + t;
        if (r < N_NODES) rowPtr[r] = beg + ex;
    }
    __syncthreads();

    for (int i = beg + t; i < end; i += 256) {
        int2 kv = temp[i];
        int rl = ((unsigned)kv.x) >> 19;
        int p  = atomicAdd(&curs[rl], 1);
        int2 out = make_int2(kv.x & 0x7FFFF, kv.y);
        if (p < CAP) stage[p] = out;
        else         colval[beg + p] = out;
    }
    __syncthreads();

    int lim = (n < CAP) ? n : CAP;
    for (int i = t; i < lim; i += 256)
        colval[beg + i] = stage[i];
}

// ---------------------------------------------------------------------------
// bf16 CSR SpMM: 16 lanes/row, lane q owns dims [4q,4q+4).
// x,y bf16 (ushort4 = 4 dims, 8B gather/lane -> 128B per edge).
// ---------------------------------------------------------------------------
__global__ void spmm_bf16_kernel(const int*  __restrict__ rp,
                                 const int2* __restrict__ cv,
                                 const ushort4* __restrict__ x4,
                                 ushort4*       __restrict__ y4) {
    int g = (blockIdx.x * blockDim.x + threadIdx.x) >> 4;   // row
    if (g >= N_NODES) return;
    int q = threadIdx.x & 15;
    int beg = rp[g];
    int end = rp[g + 1];

    float s0 = 0.f, s1 = 0.f, s2 = 0.f, s3 = 0.f;
    int i = beg;
    for (; i + 4 <= end; i += 4) {                 // 4 gathers in flight
        int2 c0 = cv[i], c1 = cv[i + 1], c2 = cv[i + 2], c3 = cv[i + 3];
        ushort4 g0 = x4[(size_t)c0.x * 16 + q];
        ushort4 g1 = x4[(size_t)c1.x * 16 + q];
        ushort4 g2 = x4[(size_t)c2.x * 16 + q];
        ushort4 g3 = x4[(size_t)c3.x * 16 + q];
        float v0 = __int_as_float(c0.y), v1 = __int_as_float(c1.y);
        float v2 = __int_as_float(c2.y), v3 = __int_as_float(c3.y);
        s0 += bf2f(g0.x) * v0; s1 += bf2f(g0.y) * v0;
        s2 += bf2f(g0.z) * v0; s3 += bf2f(g0.w) * v0;
        s0 += bf2f(g1.x) * v1; s1 += bf2f(g1.y) * v1;
        s2 += bf2f(g1.z) * v1; s3 += bf2f(g1.w) * v1;
        s0 += bf2f(g2.x) * v2; s1 += bf2f(g2.y) * v2;
        s2 += bf2f(g2.z) * v2; s3 += bf2f(g2.w) * v2;
        s0 += bf2f(g3.x) * v3; s1 += bf2f(g3.y) * v3;
        s2 += bf2f(g3.z) * v3; s3 += bf2f(g3.w) * v3;
    }
    for (; i < end; ++i) {
        int2 cc = cv[i];
        ushort4 gg = x4[(size_t)cc.x * 16 + q];
        float v = __int_as_float(cc.y);
        s0 += bf2f(gg.x) * v; s1 += bf2f(gg.y) * v;
        s2 += bf2f(gg.z) * v; s3 += bf2f(gg.w) * v;
    }

    ushort4 o;
    o.x = f2bf(s0); o.y = f2bf(s1); o.z = f2bf(s2); o.w = f2bf(s3);
    y4[(size_t)g * 16 + q] = o;
}

// ---------------------------------------------------------------------------
// final: acc = concat(u,i) + c1 + c2 + c3   (bf16 -> fp32)
// ---------------------------------------------------------------------------
__global__ void final_acc_kernel(const float* __restrict__ u,
                                 const float* __restrict__ it,
                                 const ushort4* __restrict__ c1,
                                 const ushort4* __restrict__ c2,
                                 const ushort4* __restrict__ c3,
                                 float4* __restrict__ acc,
                                 int n4u, int n4total) {
    int stride = gridDim.x * blockDim.x;
    for (int i = blockIdx.x * blockDim.x + threadIdx.x; i < n4total; i += stride) {
        float4 e = (i < n4u) ? ((const float4*)u)[i]
                             : ((const float4*)it)[i - n4u];
        ushort4 a = c1[i], b = c2[i], c = c3[i];
        e.x += bf2f(a.x) + bf2f(b.x) + bf2f(c.x);
        e.y += bf2f(a.y) + bf2f(b.y) + bf2f(c.y);
        e.z += bf2f(a.z) + bf2f(b.z) + bf2f(c.z);
        e.w += bf2f(a.w) + bf2f(b.w) + bf2f(c.w);
        acc[i] = e;
    }
}

// ---------------------------------------------------------------------------
// Fallback path: fp32 COO atomic SpMM + acc add (used if ws too small)
// ---------------------------------------------------------------------------
__global__ void copy_concat_kernel(const float* __restrict__ u,
                                   const float* __restrict__ it,
                                   float* __restrict__ cur,
                                   float* __restrict__ acc,
                                   int n4u, int n4total) {
    int stride = gridDim.x * blockDim.x;
    for (int i = blockIdx.x * blockDim.x + threadIdx.x; i < n4total; i += stride) {
        float4 v = (i < n4u) ? ((const float4*)u)[i]
                             : ((const float4*)it)[i - n4u];
        ((float4*)cur)[i] = v;
        ((float4*)acc)[i] = v;
    }
}

__global__ void spmm_atomic_kernel(const int*   __restrict__ row,
                                   const int*   __restrict__ col,
                                   const float* __restrict__ val,
                                   const float* __restrict__ x,
                                   float*       __restrict__ y) {
    const int total = N_EDGES * 16;
    int stride = gridDim.x * blockDim.x;
    for (int t = blockIdx.x * blockDim.x + threadIdx.x; t < total; t += stride) {
        int e = t >> 4;
        int q = t & 15;
        int r = row[e];
        int c = col[e];
        float v = val[e];
        float4 g = ((const float4*)x)[c * 16 + q];
        float* yp = y + r * 64 + q * 4;
        atomicAdd(yp + 0, g.x * v);
        atomicAdd(yp + 1, g.y * v);
        atomicAdd(yp + 2, g.z * v);
        atomicAdd(yp + 3, g.w * v);
    }
}

__global__ void acc_add_kernel(float* __restrict__ acc,
                               const float* __restrict__ add,
                               int n4) {
    int stride = gridDim.x * blockDim.x;
    for (int i = blockIdx.x * blockDim.x + threadIdx.x; i < n4; i += stride) {
        float4 a = ((const float4*)acc)[i];
        float4 b = ((const float4*)add)[i];
        a.x += b.x; a.y += b.y; a.z += b.z; a.w += b.w;
        ((float4*)acc)[i] = a;
    }
}

extern "C" void kernel_launch(void* const* d_in, const int* in_sizes, int n_in,
                              void* d_out, int out_size, void* d_ws, size_t ws_size,
                              hipStream_t stream) {
    const float* uEmb = (const float*)d_in[0];
    const float* iEmb = (const float*)d_in[1];
    const int*   row  = (const int*)  d_in[2];
    const int*   col  = (const int*)  d_in[3];
    const float* val  = (const float*)d_in[4];

    float* acc = (float*)d_out;

    const int n4total = N_NODES * (LATDIM / 4);       // 4.8M groups of 4
    const int n4u     = USER_N  * (LATDIM / 4);
    const size_t embBytes  = (size_t)N_NODES * LATDIM * sizeof(float);
    const size_t embBytesH = (size_t)N_NODES * LATDIM * 2;   // bf16, 38.4MB

    const int BLK = 256;
    const int GRID_MEM = 2048;

    // ---- workspace layout ----
    auto align256 = [](size_t x) { return (x + 255) & ~(size_t)255; };
    size_t off = 0;
    size_t o_cur0   = off; off += align256(embBytesH);
    size_t o_c1     = off; off += align256(embBytesH);   // temp aliases c1+c2
    size_t o_c2     = off; off += align256(embBytesH);
    size_t o_c3     = off; off += align256(embBytesH);
    size_t o_colval = off; off += align256((size_t)N_EDGES * 8);
    size_t o_rowptr = off; off += align256(((size_t)N_NODES + 1) * 4);
    size_t o_cnt    = off; off += align256((size_t)NB * GPART * 4);
    size_t o_btot   = off; off += align256((size_t)NB * 4);
    size_t o_bstart = off; off += align256(((size_t)NB + 1) * 4);
    size_t needed = off;

    char* wsb = (char*)d_ws;

    if (ws_size >= needed) {
        // ============ bf16 sorted-CSR path ============
        ushort4* cur0  = (ushort4*)(wsb + o_cur0);
        ushort4* c1    = (ushort4*)(wsb + o_c1);
        ushort4* c2    = (ushort4*)(wsb + o_c2);
        ushort4* c3    = (ushort4*)(wsb + o_c3);
        int2* colval = (int2*)(wsb + o_colval);
        int*  rowPtr = (int*) (wsb + o_rowptr);
        int*  cnt    = (int*) (wsb + o_cnt);
        int*  btot   = (int*) (wsb + o_btot);
        int*  bstart = (int*) (wsb + o_bstart);
        int2* temp   = (int2*)(wsb + o_c1);   // 76.8MB over c1+c2, freed by P5

        cvt_concat_kernel<<<GRID_MEM, BLK, 0, stream>>>(uEmb, iEmb, cur0,
                                                        n4u, n4total);

        p1_count_kernel  <<<GPART, 256, 0, stream>>>(row, cnt);
        p2_scan_kernel   <<<NB, GPART, 0, stream>>>(cnt, btot);
        p3_scan_kernel   <<<1, 1024, 0, stream>>>(btot, bstart, rowPtr);
        p4_scatter_kernel<<<GPART, 256, 0, stream>>>(row, col, val, bstart,
                                                     cnt, temp);
        bucket_sort_kernel<<<NB, 256, 0, stream>>>(bstart, temp, colval, rowPtr);

        const int GRID_SPMM = (N_NODES * 16 + BLK - 1) / BLK;   // 18750
        spmm_bf16_kernel<<<GRID_SPMM, BLK, 0, stream>>>(rowPtr, colval, cur0, c1);
        spmm_bf16_kernel<<<GRID_SPMM, BLK, 0, stream>>>(rowPtr, colval, c1,   c2);
        spmm_bf16_kernel<<<GRID_SPMM, BLK, 0, stream>>>(rowPtr, colval, c2,   c3);

        final_acc_kernel<<<GRID_MEM, BLK, 0, stream>>>(uEmb, iEmb, c1, c2, c3,
                                                       (float4*)acc,
                                                       n4u, n4total);
    } else {
        // ============ fallback: fp32 atomic path ============
        float* cur = (float*)wsb;
        float* nxt = (float*)(wsb + embBytes);
        copy_concat_kernel<<<GRID_MEM, BLK, 0, stream>>>(uEmb, iEmb, cur, acc,
                                                         n4u, n4total);
        for (int l = 0; l < N_LAYERS; ++l) {
            hipMemsetAsync(nxt, 0, embBytes, stream);
            spmm_atomic_kernel<<<4096, BLK, 0, stream>>>(row, col, val, cur, nxt);
            acc_add_kernel<<<GRID_MEM, BLK, 0, stream>>>(acc, nxt, n4total);
            float* t = cur; cur = nxt; nxt = t;
        }
    }
}